// Round 14
// baseline (177.681 us; speedup 1.0000x reference)
//
#include <hip/hip_runtime.h>

// DeBERTa disentangled attention, MI355X fp16-MFMA. R14:
// - attn: R12 verbatim (107.5us bank: time-mux band, 48KB, (256,2)).
// - gemm_all: R12 form with ONE reorder -- issueA(next) moved to AFTER the
//   staging barrier. Before: issueA sat right before a barrier that (with
//   gll16 in flight) drains vmcnt(0), exposing ~900cyc HBM A-load latency
//   every K-step. After: the A-loads drain at the NEXT top barrier with the
//   whole MFMA phase in between (R7's proven fix, applied to gemm).
// - R13's A16 pre-convert reverted (cvt traffic 112MB ~ 18us > gemm saving).

typedef _Float16 f16;
typedef f16 f16x4 __attribute__((ext_vector_type(4)));
typedef f16 f16x8 __attribute__((ext_vector_type(8)));
typedef __fp16 fp16x2 __attribute__((ext_vector_type(2)));
typedef float f32x4 __attribute__((ext_vector_type(4)));

#define D_ 768

__device__ __forceinline__ int swz(int r, int c) { return r * 64 + (c ^ ((r & 7) << 3)); }

__device__ __forceinline__ f32x4 mfma16(f16x8 a, f16x8 b, f32x4 c) {
  return __builtin_amdgcn_mfma_f32_16x16x32_f16(a, b, c, 0, 0, 0);
}

__device__ __forceinline__ f16x4 pack4(float a, float b, float c, float d) {
  fp16x2 lo = __builtin_amdgcn_cvt_pkrtz(a, b);
  fp16x2 hi = __builtin_amdgcn_cvt_pkrtz(c, d);
  f16x4 r;
  r[0] = (f16)lo[0]; r[1] = (f16)lo[1]; r[2] = (f16)hi[0]; r[3] = (f16)hi[1];
  return r;
}

__device__ __forceinline__ void gll16(const f16* g, f16* l) {
  __builtin_amdgcn_global_load_lds((const __attribute__((address_space(1))) void*)g,
                                   (__attribute__((address_space(3))) void*)l, 16, 0, 0);
}

// ---------------- W transpose + cvt (z selects weight):  Wt[n][k] = (f16) W[k][n]
__global__ __launch_bounds__(256) void wtk3(const float* __restrict__ W0, const float* __restrict__ W1,
                                            const float* __restrict__ W2, f16* __restrict__ T0,
                                            f16* __restrict__ T1, f16* __restrict__ T2) {
  __shared__ float t[32][33];
  int z = blockIdx.z;
  const float* W = z == 0 ? W0 : z == 1 ? W1 : W2;
  f16* Wt = z == 0 ? T0 : z == 1 ? T1 : T2;
  int tx = threadIdx.x, ty = threadIdx.y;  // 32 x 8
  int k0 = blockIdx.x * 32, n0 = blockIdx.y * 32;
  for (int i = ty; i < 32; i += 8) t[i][tx] = W[(k0 + i) * D_ + n0 + tx];
  __syncthreads();
  for (int i = ty; i < 32; i += 8) Wt[(n0 + i) * D_ + k0 + tx] = (f16)t[tx][i];
}

// ---------------- fused projection GEMM, one launch (grid z=5) --------------
// z0 (q,Wtq,bq,Qh,mode0) z1 (k,Wtk,bk,Kh,mode0) z2 (v,Wtv,bv,VhT,mode2)
// z3 (rel,Wtk,bk,pk,mode1,x<8) z4 (rel,Wtq,bq,pq,mode1,x<8)
__global__ __launch_bounds__(256) void gemm_all(
    const float* __restrict__ Aq, const float* __restrict__ Ak, const float* __restrict__ Av,
    const float* __restrict__ rel,
    const f16* __restrict__ Wtq, const f16* __restrict__ Wtk, const f16* __restrict__ Wtv,
    const float* __restrict__ bq, const float* __restrict__ bk, const float* __restrict__ bv,
    f16* __restrict__ Qh, f16* __restrict__ Kh, f16* __restrict__ VhT,
    f16* __restrict__ pk, f16* __restrict__ pq) {
  int z = blockIdx.z;
  if (z >= 3 && blockIdx.x >= 8) return;  // pos tables: M=1024 only
  __shared__ f16 As[128 * 64];
  __shared__ f16 Bs[128 * 64];
  const float* A; const f16* Wt; const float* bias; f16* out; int mode;
  switch (z) {
    case 0: A = Aq; Wt = Wtq; bias = bq; out = Qh; mode = 0; break;
    case 1: A = Ak; Wt = Wtk; bias = bk; out = Kh; mode = 0; break;
    case 2: A = Av; Wt = Wtv; bias = bv; out = VhT; mode = 2; break;
    case 3: A = rel; Wt = Wtk; bias = bk; out = pk; mode = 1; break;
    default: A = rel; Wt = Wtq; bias = bq; out = pq; mode = 1; break;
  }
  int tid = threadIdx.x, lane = tid & 63, wid = tid >> 6;
  int g4 = lane >> 4, l16 = lane & 15;
  int m0 = blockIdx.x * 128, n0 = blockIdx.y * 128;
  int wr = wid >> 1, wc = wid & 1;
  f32x4 acc[4][4] = {};
  float4 pfA[8];

  auto issueA = [&](int k0) {
#pragma unroll
    for (int i = 0; i < 8; i++) {
      int s = tid + i * 256, r = s >> 4, c = (s & 15) * 4;
      pfA[i] = *(const float4*)(A + (m0 + r) * D_ + k0 + c);
    }
  };

  issueA(0);
  for (int kb = 0; kb < 12; kb++) {
    int k0 = kb * 64;
    __syncthreads();  // S1: prev-iter LDS reads done (drains prev issueA here,
                      //     covered by prev MFMA phase)
#pragma unroll
    for (int i = 0; i < 4; i++) {
      int s = tid + i * 256, r = s >> 3, c = (s & 7) * 8;
      int csw = c ^ ((r & 7) << 3);
      gll16(Wt + (n0 + r) * D_ + k0 + csw, &Bs[s * 8]);
    }
#pragma unroll
    for (int i = 0; i < 8; i++) {
      int s = tid + i * 256, r = s >> 4, c = (s & 15) * 4;
      float4 x = pfA[i];
      f16x4 hv; hv[0] = (f16)x.x; hv[1] = (f16)x.y; hv[2] = (f16)x.z; hv[3] = (f16)x.w;
      *(f16x4*)&As[swz(r, c)] = hv;
    }
    __syncthreads();  // S2: drains gll + ds_writes (A-loads NOT in flight here)
    if (kb < 11) issueA(k0 + 64);  // moved after S2: drains at next S1, hidden
#pragma unroll
    for (int ks = 0; ks < 2; ks++) {
      f16x8 af[4], bf[4];
#pragma unroll
      for (int mi = 0; mi < 4; mi++) af[mi] = *(const f16x8*)&As[swz(wr * 64 + mi * 16 + l16, ks * 32 + g4 * 8)];
#pragma unroll
      for (int ni = 0; ni < 4; ni++) bf[ni] = *(const f16x8*)&Bs[swz(wc * 64 + ni * 16 + l16, ks * 32 + g4 * 8)];
#pragma unroll
      for (int mi = 0; mi < 4; mi++)
#pragma unroll
        for (int ni = 0; ni < 4; ni++) acc[mi][ni] = mfma16(af[mi], bf[ni], acc[mi][ni]);
    }
  }
#pragma unroll
  for (int mi = 0; mi < 4; mi++)
#pragma unroll
    for (int ni = 0; ni < 4; ni++) {
      int mb = m0 + wr * 64 + mi * 16 + g4 * 4;  // j=0 row
      int n = n0 + wc * 64 + ni * 16 + l16;
      int h = n >> 6, hd = n & 63;
      if (mode == 2) {
        int b = mb >> 9, s = mb & 511;
        f16x4 hv;
#pragma unroll
        for (int j = 0; j < 4; j++) hv[j] = (f16)(acc[mi][ni][j] + bias[n]);
        *(f16x4*)&out[(((b * 12 + h) * 64) + hd) * 512 + s] = hv;
      } else {
#pragma unroll
        for (int j = 0; j < 4; j++) {
          int m = mb + j;
          float v = acc[mi][ni][j] + bias[n];
          int idx;
          if (mode == 0) {
            int b = m >> 9, s = m & 511;
            idx = (((b * 12 + h) * 512) + s) * 64 + hd;
          } else {
            idx = ((h * 1024) + m) * 64 + hd;
          }
          out[idx] = (f16)v;
        }
      }
    }
}

// ---------------- fused disentangled attention (R12 verbatim) ---------------
// flat grid 1536 blocks (XCD-swizzled), 256 threads (4 waves). QBLK=KBLK=64.
// Lane owns q-row qrow; scores S^T[k][q] via mfma(K,Q). Single band buffer
// committed twice per iter (Bcp then Bpq): 48KB LDS -> 3 blocks/CU
// (LDS-governed; launch_bounds floor stays 2 -- R11 spill lesson).
__global__ __launch_bounds__(256, 2) void attn(const f16* __restrict__ Qh, const f16* __restrict__ Kh,
                                               const f16* __restrict__ VhT, const f16* __restrict__ posk,
                                               const f16* __restrict__ posq, float* __restrict__ out) {
  __shared__ f16 Ks_[64 * 64];    // 8 KB  [k][d]
  __shared__ f16 Vts[64 * 64];    // 8 KB  [d][k]
  __shared__ f16 Bband[128 * 64]; // 16 KB band rows [r][d]: Bcp, then Bpq
  __shared__ f16 bsA[64 * 64];    // 8 KB  c2p gathered [q][k]; P after softmax
  __shared__ f16 bs2[64 * 64];    // 8 KB  p2c gathered [q][k]

  int tid = threadIdx.x, lane = tid & 63, wid = tid >> 6;
  int g4 = lane >> 4, l16 = lane & 15;
  int flat = blockIdx.x;
  int work = (flat & 7) * 192 + (flat >> 3);
  int q0 = (work & 7) * 64;
  int hb = work >> 3;
  int h = hb % 12, b = hb / 12;

  const f16* Qg = Qh + (b * 12 + h) * 512 * 64;
  const f16* Kg = Kh + (b * 12 + h) * 512 * 64;
  const f16* Vg = VhT + (b * 12 + h) * 64 * 512;  // [d][s]
  const f16* PKg = posk + h * 1024 * 64;
  const f16* PQg = posq + h * 1024 * 64;

  int qrow = wid * 16 + l16;
  f16x8 qf[2];
#pragma unroll
  for (int ks = 0; ks < 2; ks++) qf[ks] = *(const f16x8*)(Qg + (q0 + qrow) * 64 + ks * 32 + g4 * 8);

  f16x8 pfK[2], pfV[2], pfC[4], pfP[4];

  auto issue = [&](int kb) {
    int k0 = kb * 64, pbase = q0 - k0 + 449;
#pragma unroll
    for (int i = 0; i < 2; i++) {
      int s = tid + i * 256, r = s >> 3, c = (s & 7) * 8;
      pfK[i] = *(const f16x8*)(Kg + (k0 + r) * 64 + c);
      pfV[i] = *(const f16x8*)(Vg + r * 512 + k0 + c);
    }
#pragma unroll
    for (int i = 0; i < 4; i++) {
      int s = tid + i * 256, r = s >> 3, c = (s & 7) * 8;
      int prow = pbase + r;
      prow = prow > 1023 ? 1023 : prow;
      pfC[i] = *(const f16x8*)(PKg + prow * 64 + c);
      pfP[i] = *(const f16x8*)(PQg + prow * 64 + c);
    }
  };
  auto commitKVC = [&]() {
#pragma unroll
    for (int i = 0; i < 2; i++) {
      int s = tid + i * 256, r = s >> 3, c = (s & 7) * 8;
      *(f16x8*)&Ks_[swz(r, c)] = pfK[i];
      *(f16x8*)&Vts[swz(r, c)] = pfV[i];
    }
#pragma unroll
    for (int i = 0; i < 4; i++) {
      int s = tid + i * 256, r = s >> 3, c = (s & 7) * 8;
      *(f16x8*)&Bband[swz(r, c)] = pfC[i];
    }
  };
  auto commitP = [&]() {
#pragma unroll
    for (int i = 0; i < 4; i++) {
      int s = tid + i * 256, r = s >> 3, c = (s & 7) * 8;
      *(f16x8*)&Bband[swz(r, c)] = pfP[i];
    }
  };

  float mx = -1e30f, lpart = 0.f;
  f32x4 ctx[4] = {};
  const float scale2 = 0.07216878364870323f * 1.4426950408889634f;  // 1/sqrt(192)*log2e

  issue(0);
  for (int kb = 0; kb < 8; kb++) {
    commitKVC();
    __syncthreads();  // S1

    f16x8 kfw[2], kf[2][4], vf[2][4];
#pragma unroll
    for (int ks = 0; ks < 2; ks++) {
      kfw[ks] = *(const f16x8*)&Ks_[swz(qrow, ks * 32 + g4 * 8)];
#pragma unroll
      for (int ni = 0; ni < 4; ni++) {
        kf[ks][ni] = *(const f16x8*)&Ks_[swz(ni * 16 + l16, ks * 32 + g4 * 8)];
        vf[ks][ni] = *(const f16x8*)&Vts[swz(ni * 16 + l16, ks * 32 + g4 * 8)];
      }
    }
    __builtin_amdgcn_s_setprio(1);
    f32x4 sc[4] = {};
#pragma unroll
    for (int ks = 0; ks < 2; ks++)
#pragma unroll
      for (int ni = 0; ni < 4; ni++) sc[ni] = mfma16(kf[ks][ni], qf[ks], sc[ni]);

#pragma unroll
    for (int t = 0; t < 5; t++) {
      int mi = wid + t;
      f32x4 a2 = {};
#pragma unroll
      for (int ks = 0; ks < 2; ks++) {
        f16x8 bp = *(const f16x8*)&Bband[swz(mi * 16 + l16, ks * 32 + g4 * 8)];
        a2 = mfma16(bp, qf[ks], a2);
      }
      int plocb = mi * 16 + g4 * 4;
#pragma unroll
      for (int j = 0; j < 4; j++) {
        int kk = qrow - (plocb + j) + 63;
        if (kk >= 0 && kk < 64) bsA[swz(qrow, kk)] = (f16)a2[j];
      }
    }
    __builtin_amdgcn_s_setprio(0);
    __syncthreads();  // S2
    commitP();
    __syncthreads();  // S3

    __builtin_amdgcn_s_setprio(1);
#pragma unroll
    for (int t = 0; t < 5; t++) {
      int nb = 3 - wid + t;
      f32x4 a2 = {};
#pragma unroll
      for (int ks = 0; ks < 2; ks++) {
        f16x8 bq_ = *(const f16x8*)&Bband[swz(nb * 16 + l16, ks * 32 + g4 * 8)];
        a2 = mfma16(kfw[ks], bq_, a2);
      }
#pragma unroll
      for (int j = 0; j < 4; j++) {
        int kk = wid * 16 + g4 * 4 + j;
        int qq = nb * 16 + l16 + kk - 63;
        if (qq >= 0 && qq < 64) bs2[swz(qq, kk)] = (f16)a2[j];
      }
    }
    __builtin_amdgcn_s_setprio(0);
    __syncthreads();  // S4
    if (kb < 7) issue(kb + 1);

    f16x4 pa4[4], pc4[4];
#pragma unroll
    for (int ni = 0; ni < 4; ni++) {
      int kb4 = ni * 16 + g4 * 4;
      pa4[ni] = *(const f16x4*)&bsA[swz(qrow, kb4)];
      pc4[ni] = *(const f16x4*)&bs2[swz(qrow, kb4)];
    }
    float mt = -1e30f;
#pragma unroll
    for (int ni = 0; ni < 4; ni++)
#pragma unroll
      for (int j = 0; j < 4; j++) {
        float v = (sc[ni][j] + (float)pa4[ni][j] + (float)pc4[ni][j]) * scale2;
        sc[ni][j] = v;
        mt = fmaxf(mt, v);
      }
    if (!__all(mt <= mx + 6.0f)) {
      float m2 = fmaxf(mt, __shfl_xor(mt, 16, 64));
      m2 = fmaxf(m2, __shfl_xor(m2, 32, 64));
      float corr = __builtin_amdgcn_exp2f(mx - m2);
      mx = m2;
      lpart *= corr;
#pragma unroll
      for (int mi = 0; mi < 4; mi++) ctx[mi] *= corr;
    }
    float rs = 0.f;
#pragma unroll
    for (int ni = 0; ni < 4; ni++) {
      float p0 = __builtin_amdgcn_exp2f(sc[ni][0] - mx);
      float p1 = __builtin_amdgcn_exp2f(sc[ni][1] - mx);
      float p2 = __builtin_amdgcn_exp2f(sc[ni][2] - mx);
      float p3 = __builtin_amdgcn_exp2f(sc[ni][3] - mx);
      rs += (p0 + p1) + (p2 + p3);
      *(f16x4*)&bsA[swz(qrow, ni * 16 + g4 * 4)] = pack4(p0, p1, p2, p3);
    }
    lpart += rs;

    f16x8 pa[2];
#pragma unroll
    for (int ks = 0; ks < 2; ks++) pa[ks] = *(const f16x8*)&bsA[swz(qrow, ks * 32 + g4 * 8)];
    __builtin_amdgcn_s_setprio(1);
#pragma unroll
    for (int mi = 0; mi < 4; mi++)
#pragma unroll
      for (int ks = 0; ks < 2; ks++) ctx[mi] = mfma16(vf[ks][mi], pa[ks], ctx[mi]);
    __builtin_amdgcn_s_setprio(0);
  }
  float ls = lpart;
  ls += __shfl_xor(ls, 16, 64);
  ls += __shfl_xor(ls, 32, 64);
  float inv_l = 1.0f / ls;
#pragma unroll
  for (int mi = 0; mi < 4; mi++) {
    float4 o;
    o.x = ctx[mi][0] * inv_l;
    o.y = ctx[mi][1] * inv_l;
    o.z = ctx[mi][2] * inv_l;
    o.w = ctx[mi][3] * inv_l;
    *(float4*)&out[(b * 512 + q0 + qrow) * 768 + h * 64 + mi * 16 + g4 * 4] = o;
  }
}

extern "C" void kernel_launch(void* const* d_in, const int* in_sizes, int n_in,
                              void* d_out, int out_size, void* d_ws, size_t ws_size,
                              hipStream_t stream) {
  const float* q = (const float*)d_in[0];
  const float* k = (const float*)d_in[1];
  const float* v = (const float*)d_in[2];
  const float* rel = (const float*)d_in[3];
  const float* Wq = (const float*)d_in[4];
  const float* bq = (const float*)d_in[5];
  const float* Wk = (const float*)d_in[6];
  const float* bk = (const float*)d_in[7];
  const float* Wv = (const float*)d_in[8];
  const float* bv = (const float*)d_in[9];
  float* out = (float*)d_out;

  f16* ws = (f16*)d_ws;
  f16* Wtq = ws;
  f16* Wtk = Wtq + 589824;
  f16* Wtv = Wtk + 589824;
  f16* Qh = Wtv + 589824;
  f16* Kh = Qh + 6291456;
  f16* VhT = Kh + 6291456;
  f16* pk = VhT + 6291456;
  f16* pq = pk + 786432;

  wtk3<<<dim3(24, 24, 3), dim3(32, 8), 0, stream>>>(Wq, Wk, Wv, Wtq, Wtk, Wtv);
  gemm_all<<<dim3(64, 6, 5), 256, 0, stream>>>(q, k, v, rel, Wtq, Wtk, Wtv,
                                               bq, bk, bv, Qh, Kh, VhT, pk, pq);
  attn<<<dim3(1536), 256, 0, stream>>>(Qh, Kh, VhT, pk, pq, out);
}

// Round 15
// 163.585 us; speedup vs baseline: 1.0862x; 1.0862x over previous
//
#include <hip/hip_runtime.h>

// DeBERTa disentangled attention, MI355X fp16-MFMA. R15:
// - gemm_all/wtk3: R12 verbatim (measured best; R14 reorder was noise).
// - attn: R12 skeleton with Vts LDS staging REMOVED -- V^T fragments are
//   wave-independent addresses, so read direct from global (L2 broadcast
//   across the 4 waves). Issued in frag phase (after S1), drained at S2
//   under the c2c+c2p MFMA cover. LDS 48->40KB (4 blocks/CU), -10 DS
//   ops/lane-iter. Single variable vs R12; barrier skeleton untouched.

typedef _Float16 f16;
typedef f16 f16x4 __attribute__((ext_vector_type(4)));
typedef f16 f16x8 __attribute__((ext_vector_type(8)));
typedef __fp16 fp16x2 __attribute__((ext_vector_type(2)));
typedef float f32x4 __attribute__((ext_vector_type(4)));

#define D_ 768

__device__ __forceinline__ int swz(int r, int c) { return r * 64 + (c ^ ((r & 7) << 3)); }

__device__ __forceinline__ f32x4 mfma16(f16x8 a, f16x8 b, f32x4 c) {
  return __builtin_amdgcn_mfma_f32_16x16x32_f16(a, b, c, 0, 0, 0);
}

__device__ __forceinline__ f16x4 pack4(float a, float b, float c, float d) {
  fp16x2 lo = __builtin_amdgcn_cvt_pkrtz(a, b);
  fp16x2 hi = __builtin_amdgcn_cvt_pkrtz(c, d);
  f16x4 r;
  r[0] = (f16)lo[0]; r[1] = (f16)lo[1]; r[2] = (f16)hi[0]; r[3] = (f16)hi[1];
  return r;
}

__device__ __forceinline__ void gll16(const f16* g, f16* l) {
  __builtin_amdgcn_global_load_lds((const __attribute__((address_space(1))) void*)g,
                                   (__attribute__((address_space(3))) void*)l, 16, 0, 0);
}

// ---------------- W transpose + cvt (z selects weight):  Wt[n][k] = (f16) W[k][n]
__global__ __launch_bounds__(256) void wtk3(const float* __restrict__ W0, const float* __restrict__ W1,
                                            const float* __restrict__ W2, f16* __restrict__ T0,
                                            f16* __restrict__ T1, f16* __restrict__ T2) {
  __shared__ float t[32][33];
  int z = blockIdx.z;
  const float* W = z == 0 ? W0 : z == 1 ? W1 : W2;
  f16* Wt = z == 0 ? T0 : z == 1 ? T1 : T2;
  int tx = threadIdx.x, ty = threadIdx.y;  // 32 x 8
  int k0 = blockIdx.x * 32, n0 = blockIdx.y * 32;
  for (int i = ty; i < 32; i += 8) t[i][tx] = W[(k0 + i) * D_ + n0 + tx];
  __syncthreads();
  for (int i = ty; i < 32; i += 8) Wt[(n0 + i) * D_ + k0 + tx] = (f16)t[tx][i];
}

// ---------------- fused projection GEMM, one launch (grid z=5), R12 form ----
__global__ __launch_bounds__(256) void gemm_all(
    const float* __restrict__ Aq, const float* __restrict__ Ak, const float* __restrict__ Av,
    const float* __restrict__ rel,
    const f16* __restrict__ Wtq, const f16* __restrict__ Wtk, const f16* __restrict__ Wtv,
    const float* __restrict__ bq, const float* __restrict__ bk, const float* __restrict__ bv,
    f16* __restrict__ Qh, f16* __restrict__ Kh, f16* __restrict__ VhT,
    f16* __restrict__ pk, f16* __restrict__ pq) {
  int z = blockIdx.z;
  if (z >= 3 && blockIdx.x >= 8) return;  // pos tables: M=1024 only
  __shared__ f16 As[128 * 64];
  __shared__ f16 Bs[128 * 64];
  const float* A; const f16* Wt; const float* bias; f16* out; int mode;
  switch (z) {
    case 0: A = Aq; Wt = Wtq; bias = bq; out = Qh; mode = 0; break;
    case 1: A = Ak; Wt = Wtk; bias = bk; out = Kh; mode = 0; break;
    case 2: A = Av; Wt = Wtv; bias = bv; out = VhT; mode = 2; break;
    case 3: A = rel; Wt = Wtk; bias = bk; out = pk; mode = 1; break;
    default: A = rel; Wt = Wtq; bias = bq; out = pq; mode = 1; break;
  }
  int tid = threadIdx.x, lane = tid & 63, wid = tid >> 6;
  int g4 = lane >> 4, l16 = lane & 15;
  int m0 = blockIdx.x * 128, n0 = blockIdx.y * 128;
  int wr = wid >> 1, wc = wid & 1;
  f32x4 acc[4][4] = {};
  float4 pfA[8];

  auto issueA = [&](int k0) {
#pragma unroll
    for (int i = 0; i < 8; i++) {
      int s = tid + i * 256, r = s >> 4, c = (s & 15) * 4;
      pfA[i] = *(const float4*)(A + (m0 + r) * D_ + k0 + c);
    }
  };

  issueA(0);
  for (int kb = 0; kb < 12; kb++) {
    int k0 = kb * 64;
    __syncthreads();  // prev-iter LDS reads done
#pragma unroll
    for (int i = 0; i < 4; i++) {
      int s = tid + i * 256, r = s >> 3, c = (s & 7) * 8;
      int csw = c ^ ((r & 7) << 3);
      gll16(Wt + (n0 + r) * D_ + k0 + csw, &Bs[s * 8]);
    }
#pragma unroll
    for (int i = 0; i < 8; i++) {
      int s = tid + i * 256, r = s >> 4, c = (s & 15) * 4;
      float4 x = pfA[i];
      f16x4 hv; hv[0] = (f16)x.x; hv[1] = (f16)x.y; hv[2] = (f16)x.z; hv[3] = (f16)x.w;
      *(f16x4*)&As[swz(r, c)] = hv;
    }
    if (kb < 11) issueA(k0 + 64);
    __syncthreads();  // drains gll + ds_writes
#pragma unroll
    for (int ks = 0; ks < 2; ks++) {
      f16x8 af[4], bf[4];
#pragma unroll
      for (int mi = 0; mi < 4; mi++) af[mi] = *(const f16x8*)&As[swz(wr * 64 + mi * 16 + l16, ks * 32 + g4 * 8)];
#pragma unroll
      for (int ni = 0; ni < 4; ni++) bf[ni] = *(const f16x8*)&Bs[swz(wc * 64 + ni * 16 + l16, ks * 32 + g4 * 8)];
#pragma unroll
      for (int mi = 0; mi < 4; mi++)
#pragma unroll
        for (int ni = 0; ni < 4; ni++) acc[mi][ni] = mfma16(af[mi], bf[ni], acc[mi][ni]);
    }
  }
#pragma unroll
  for (int mi = 0; mi < 4; mi++)
#pragma unroll
    for (int ni = 0; ni < 4; ni++) {
      int mb = m0 + wr * 64 + mi * 16 + g4 * 4;  // j=0 row
      int n = n0 + wc * 64 + ni * 16 + l16;
      int h = n >> 6, hd = n & 63;
      if (mode == 2) {
        int b = mb >> 9, s = mb & 511;
        f16x4 hv;
#pragma unroll
        for (int j = 0; j < 4; j++) hv[j] = (f16)(acc[mi][ni][j] + bias[n]);
        *(f16x4*)&out[(((b * 12 + h) * 64) + hd) * 512 + s] = hv;
      } else {
#pragma unroll
        for (int j = 0; j < 4; j++) {
          int m = mb + j;
          float v = acc[mi][ni][j] + bias[n];
          int idx;
          if (mode == 0) {
            int b = m >> 9, s = m & 511;
            idx = (((b * 12 + h) * 512) + s) * 64 + hd;
          } else {
            idx = ((h * 1024) + m) * 64 + hd;
          }
          out[idx] = (f16)v;
        }
      }
    }
}

// ---------------- fused disentangled attention ----------------
// flat grid 1536 blocks (XCD-swizzled), 256 threads (4 waves). QBLK=KBLK=64.
// Lane owns q-row qrow; scores S^T[k][q] via mfma(K,Q). Single band buffer
// committed twice per iter (Bcp then Bpq). V^T fragments direct from global
// (wave-independent addresses -> L2 broadcast); K staged (cross-wave reuse
// with per-wave rows). 40KB LDS -> 4 blocks/CU; launch_bounds floor 2.
__global__ __launch_bounds__(256, 2) void attn(const f16* __restrict__ Qh, const f16* __restrict__ Kh,
                                               const f16* __restrict__ VhT, const f16* __restrict__ posk,
                                               const f16* __restrict__ posq, float* __restrict__ out) {
  __shared__ f16 Ks_[64 * 64];    // 8 KB  [k][d]
  __shared__ f16 Bband[128 * 64]; // 16 KB band rows [r][d]: Bcp, then Bpq
  __shared__ f16 bsA[64 * 64];    // 8 KB  c2p gathered [q][k]; P after softmax
  __shared__ f16 bs2[64 * 64];    // 8 KB  p2c gathered [q][k]

  int tid = threadIdx.x, lane = tid & 63, wid = tid >> 6;
  int g4 = lane >> 4, l16 = lane & 15;
  int flat = blockIdx.x;
  int work = (flat & 7) * 192 + (flat >> 3);
  int q0 = (work & 7) * 64;
  int hb = work >> 3;
  int h = hb % 12, b = hb / 12;

  const f16* Qg = Qh + (b * 12 + h) * 512 * 64;
  const f16* Kg = Kh + (b * 12 + h) * 512 * 64;
  const f16* Vg = VhT + (b * 12 + h) * 64 * 512;  // [d][s]
  const f16* PKg = posk + h * 1024 * 64;
  const f16* PQg = posq + h * 1024 * 64;

  int qrow = wid * 16 + l16;
  f16x8 qf[2];
#pragma unroll
  for (int ks = 0; ks < 2; ks++) qf[ks] = *(const f16x8*)(Qg + (q0 + qrow) * 64 + ks * 32 + g4 * 8);

  f16x8 pfK[2], pfC[4], pfP[4];

  auto issue = [&](int kb) {
    int k0 = kb * 64, pbase = q0 - k0 + 449;
#pragma unroll
    for (int i = 0; i < 2; i++) {
      int s = tid + i * 256, r = s >> 3, c = (s & 7) * 8;
      pfK[i] = *(const f16x8*)(Kg + (k0 + r) * 64 + c);
    }
#pragma unroll
    for (int i = 0; i < 4; i++) {
      int s = tid + i * 256, r = s >> 3, c = (s & 7) * 8;
      int prow = pbase + r;
      prow = prow > 1023 ? 1023 : prow;
      pfC[i] = *(const f16x8*)(PKg + prow * 64 + c);
      pfP[i] = *(const f16x8*)(PQg + prow * 64 + c);
    }
  };
  auto commitKC = [&]() {
#pragma unroll
    for (int i = 0; i < 2; i++) {
      int s = tid + i * 256, r = s >> 3, c = (s & 7) * 8;
      *(f16x8*)&Ks_[swz(r, c)] = pfK[i];
    }
#pragma unroll
    for (int i = 0; i < 4; i++) {
      int s = tid + i * 256, r = s >> 3, c = (s & 7) * 8;
      *(f16x8*)&Bband[swz(r, c)] = pfC[i];
    }
  };
  auto commitP = [&]() {
#pragma unroll
    for (int i = 0; i < 4; i++) {
      int s = tid + i * 256, r = s >> 3, c = (s & 7) * 8;
      *(f16x8*)&Bband[swz(r, c)] = pfP[i];
    }
  };

  float mx = -1e30f, lpart = 0.f;
  f32x4 ctx[4] = {};
  const float scale2 = 0.07216878364870323f * 1.4426950408889634f;  // 1/sqrt(192)*log2e

  issue(0);
  for (int kb = 0; kb < 8; kb++) {
    int k0 = kb * 64;
    commitKC();
    __syncthreads();  // S1

    // ---- fragment reads: K from LDS; V^T DIRECT from global (wave-indep
    //      addresses; issued here, drained at S2 under c2c+c2p MFMA cover) --
    f16x8 kfw[2], kf[2][4], vf[2][4];
#pragma unroll
    for (int ks = 0; ks < 2; ks++) {
      kfw[ks] = *(const f16x8*)&Ks_[swz(qrow, ks * 32 + g4 * 8)];
#pragma unroll
      for (int ni = 0; ni < 4; ni++) {
        kf[ks][ni] = *(const f16x8*)&Ks_[swz(ni * 16 + l16, ks * 32 + g4 * 8)];
        vf[ks][ni] = *(const f16x8*)(Vg + (ni * 16 + l16) * 512 + k0 + ks * 32 + g4 * 8);
      }
    }
    __builtin_amdgcn_s_setprio(1);
    f32x4 sc[4] = {};
#pragma unroll
    for (int ks = 0; ks < 2; ks++)
#pragma unroll
      for (int ni = 0; ni < 4; ni++) sc[ni] = mfma16(kf[ks][ni], qf[ks], sc[ni]);

#pragma unroll
    for (int t = 0; t < 5; t++) {
      int mi = wid + t;
      f32x4 a2 = {};
#pragma unroll
      for (int ks = 0; ks < 2; ks++) {
        f16x8 bp = *(const f16x8*)&Bband[swz(mi * 16 + l16, ks * 32 + g4 * 8)];
        a2 = mfma16(bp, qf[ks], a2);
      }
      int plocb = mi * 16 + g4 * 4;
#pragma unroll
      for (int j = 0; j < 4; j++) {
        int kk = qrow - (plocb + j) + 63;
        if (kk >= 0 && kk < 64) bsA[swz(qrow, kk)] = (f16)a2[j];
      }
    }
    __builtin_amdgcn_s_setprio(0);
    __syncthreads();  // S2
    commitP();
    __syncthreads();  // S3

    __builtin_amdgcn_s_setprio(1);
#pragma unroll
    for (int t = 0; t < 5; t++) {
      int nb = 3 - wid + t;
      f32x4 a2 = {};
#pragma unroll
      for (int ks = 0; ks < 2; ks++) {
        f16x8 bq_ = *(const f16x8*)&Bband[swz(nb * 16 + l16, ks * 32 + g4 * 8)];
        a2 = mfma16(kfw[ks], bq_, a2);
      }
#pragma unroll
      for (int j = 0; j < 4; j++) {
        int kk = wid * 16 + g4 * 4 + j;
        int qq = nb * 16 + l16 + kk - 63;
        if (qq >= 0 && qq < 64) bs2[swz(qq, kk)] = (f16)a2[j];
      }
    }
    __builtin_amdgcn_s_setprio(0);
    __syncthreads();  // S4
    if (kb < 7) issue(kb + 1);

    f16x4 pa4[4], pc4[4];
#pragma unroll
    for (int ni = 0; ni < 4; ni++) {
      int kb4 = ni * 16 + g4 * 4;
      pa4[ni] = *(const f16x4*)&bsA[swz(qrow, kb4)];
      pc4[ni] = *(const f16x4*)&bs2[swz(qrow, kb4)];
    }
    float mt = -1e30f;
#pragma unroll
    for (int ni = 0; ni < 4; ni++)
#pragma unroll
      for (int j = 0; j < 4; j++) {
        float v = (sc[ni][j] + (float)pa4[ni][j] + (float)pc4[ni][j]) * scale2;
        sc[ni][j] = v;
        mt = fmaxf(mt, v);
      }
    if (!__all(mt <= mx + 6.0f)) {
      float m2 = fmaxf(mt, __shfl_xor(mt, 16, 64));
      m2 = fmaxf(m2, __shfl_xor(m2, 32, 64));
      float corr = __builtin_amdgcn_exp2f(mx - m2);
      mx = m2;
      lpart *= corr;
#pragma unroll
      for (int mi = 0; mi < 4; mi++) ctx[mi] *= corr;
    }
    float rs = 0.f;
#pragma unroll
    for (int ni = 0; ni < 4; ni++) {
      float p0 = __builtin_amdgcn_exp2f(sc[ni][0] - mx);
      float p1 = __builtin_amdgcn_exp2f(sc[ni][1] - mx);
      float p2 = __builtin_amdgcn_exp2f(sc[ni][2] - mx);
      float p3 = __builtin_amdgcn_exp2f(sc[ni][3] - mx);
      rs += (p0 + p1) + (p2 + p3);
      *(f16x4*)&bsA[swz(qrow, ni * 16 + g4 * 4)] = pack4(p0, p1, p2, p3);
    }
    lpart += rs;

    f16x8 pa[2];
#pragma unroll
    for (int ks = 0; ks < 2; ks++) pa[ks] = *(const f16x8*)&bsA[swz(qrow, ks * 32 + g4 * 8)];
    __builtin_amdgcn_s_setprio(1);
#pragma unroll
    for (int mi = 0; mi < 4; mi++)
#pragma unroll
      for (int ks = 0; ks < 2; ks++) ctx[mi] = mfma16(vf[ks][mi], pa[ks], ctx[mi]);
    __builtin_amdgcn_s_setprio(0);
  }
  float ls = lpart;
  ls += __shfl_xor(ls, 16, 64);
  ls += __shfl_xor(ls, 32, 64);
  float inv_l = 1.0f / ls;
#pragma unroll
  for (int mi = 0; mi < 4; mi++) {
    float4 o;
    o.x = ctx[mi][0] * inv_l;
    o.y = ctx[mi][1] * inv_l;
    o.z = ctx[mi][2] * inv_l;
    o.w = ctx[mi][3] * inv_l;
    *(float4*)&out[(b * 512 + q0 + qrow) * 768 + h * 64 + mi * 16 + g4 * 4] = o;
  }
}

extern "C" void kernel_launch(void* const* d_in, const int* in_sizes, int n_in,
                              void* d_out, int out_size, void* d_ws, size_t ws_size,
                              hipStream_t stream) {
  const float* q = (const float*)d_in[0];
  const float* k = (const float*)d_in[1];
  const float* v = (const float*)d_in[2];
  const float* rel = (const float*)d_in[3];
  const float* Wq = (const float*)d_in[4];
  const float* bq = (const float*)d_in[5];
  const float* Wk = (const float*)d_in[6];
  const float* bk = (const float*)d_in[7];
  const float* Wv = (const float*)d_in[8];
  const float* bv = (const float*)d_in[9];
  float* out = (float*)d_out;

  f16* ws = (f16*)d_ws;
  f16* Wtq = ws;
  f16* Wtk = Wtq + 589824;
  f16* Wtv = Wtk + 589824;
  f16* Qh = Wtv + 589824;
  f16* Kh = Qh + 6291456;
  f16* VhT = Kh + 6291456;
  f16* pk = VhT + 6291456;
  f16* pq = pk + 786432;

  wtk3<<<dim3(24, 24, 3), dim3(32, 8), 0, stream>>>(Wq, Wk, Wv, Wtq, Wtk, Wtv);
  gemm_all<<<dim3(64, 6, 5), 256, 0, stream>>>(q, k, v, rel, Wtq, Wtk, Wtv,
                                               bq, bk, bv, Qh, Kh, VhT, pk, pq);
  attn<<<dim3(1536), 256, 0, stream>>>(Qh, Kh, VhT, pk, pq, out);
}